// Round 1
// baseline (1226.952 us; speedup 1.0000x reference)
//
#include <hip/hip_runtime.h>
#include <hip/hip_bf16.h>

// Problem constants (from reference)
#define BB 4
#define LL 2048
#define DM 1024
#define NH 16
#define FEAT 16
#define HD 64
#define CHUNK 128
#define NCHUNK (LL / CHUNK)   // 16
#define DE 273                // 1 + 16 + 256
#define EPS 1e-12f
#define INV_R2RD 0.17677669529663688f   // 1/(sqrt(2)*sqrt(16))

// ---------------------------------------------------------------------------
// Generic fp32 GEMM: C[M,N] = A[M,K] @ Bw[N,K]^T   (M,N %64==0, K%16==0)
// 64x64 tile, 256 threads, 4x4 micro-tile, BK=16.
// ---------------------------------------------------------------------------
__global__ __launch_bounds__(256)
void gemm_abt(const float* __restrict__ A, const float* __restrict__ Bw,
              float* __restrict__ C, int M, int N, int K)
{
    __shared__ __align__(16) float As[16][64];
    __shared__ __align__(16) float Bs[16][64];
    const int tid = threadIdx.x;
    const int m0 = blockIdx.y * 64;
    const int n0 = blockIdx.x * 64;
    const int tx = tid & 15, ty = tid >> 4;
    const int lr = tid >> 2;         // 0..63 (tile row)
    const int lk = (tid & 3) << 2;   // 0,4,8,12

    float acc[4][4] = {};

    for (int k0 = 0; k0 < K; k0 += 16) {
        float4 a4 = *(const float4*)(A  + (size_t)(m0 + lr) * K + k0 + lk);
        float4 b4 = *(const float4*)(Bw + (size_t)(n0 + lr) * K + k0 + lk);
        As[lk + 0][lr] = a4.x; As[lk + 1][lr] = a4.y;
        As[lk + 2][lr] = a4.z; As[lk + 3][lr] = a4.w;
        Bs[lk + 0][lr] = b4.x; Bs[lk + 1][lr] = b4.y;
        Bs[lk + 2][lr] = b4.z; Bs[lk + 3][lr] = b4.w;
        __syncthreads();
#pragma unroll
        for (int kk = 0; kk < 16; ++kk) {
            float a[4], b[4];
#pragma unroll
            for (int u = 0; u < 4; ++u) { a[u] = As[kk][ty * 4 + u]; b[u] = Bs[kk][tx * 4 + u]; }
#pragma unroll
            for (int i = 0; i < 4; ++i)
#pragma unroll
                for (int j = 0; j < 4; ++j) acc[i][j] += a[i] * b[j];
        }
        __syncthreads();
    }
#pragma unroll
    for (int i = 0; i < 4; ++i) {
        float4 st = { acc[i][0], acc[i][1], acc[i][2], acc[i][3] };
        *(float4*)(C + (size_t)(m0 + ty * 4 + i) * N + n0 + tx * 4) = st;
    }
}

// ---------------------------------------------------------------------------
// Chunked causal Taylor linear attention.
// Grid: 256 blocks = (b, h, e-split of 4). Each block owns a 16-wide slice of
// HEAD_DIM and keeps S[273][16] + z[273] in LDS across the 16 chunks.
// Intra-chunk scores use the collapsed form a = 1 + s + s^2/2, s = q.k/4.
// 256 threads:
//   stage 2 (y): thread = (row-pair it 0..63, e-group eg 0..3): 2x4 outputs
//   stage 3 (S): thread = (f1 0..15, f2-group 0..3, eg 0..3): 4x4 outer-prod
// ---------------------------------------------------------------------------
__global__ __launch_bounds__(256)
void attn_kernel(const float* __restrict__ qg, const float* __restrict__ kg,
                 const float* __restrict__ vg, float* __restrict__ yg)
{
    __shared__ __align__(16) float Ss[DE][16];
    __shared__ float zs[DE];
    __shared__ __align__(16) float qs[CHUNK][16];
    __shared__ __align__(16) float ks[CHUNK][16];
    __shared__ __align__(16) float vs[CHUNK][16];

    const int bid = blockIdx.x;
    const int b  = bid >> 6;          // 0..3
    const int h  = (bid >> 2) & 15;   // 0..15
    const int es = bid & 3;           // e-slice 0..3 (16 cols each)
    const int tid = threadIdx.x;

    // init state
    for (int i = tid; i < DE * 16; i += 256) ((float*)Ss)[i] = 0.f;
    for (int i = tid; i < DE; i += 256) zs[i] = 0.f;

    const int it = tid >> 2, eg = tid & 3;
    const int i0r = it * 2, i1r = i0r + 1;
    const int f1  = tid >> 4;            // stage-3 roles
    const int f2g = (tid >> 2) & 3;

    for (int c = 0; c < NCHUNK; ++c) {
        __syncthreads();   // guards init / previous stage-3 vs new loads
        const size_t rowbase = (size_t)(b * LL + c * CHUNK);
        for (int idx = tid; idx < 512; idx += 256) {
            int row = idx >> 2, f4 = (idx & 3) << 2;
            *(float4*)&qs[row][f4] = *(const float4*)(qg + (rowbase + row) * 256  + h * 16 + f4);
            *(float4*)&ks[row][f4] = *(const float4*)(kg + (rowbase + row) * 256  + h * 16 + f4);
            *(float4*)&vs[row][f4] = *(const float4*)(vg + (rowbase + row) * 1024 + h * 64 + es * 16 + f4);
        }
        __syncthreads();

        // ---- stage 2: y = (masked poly-attn)@v + qf@S, den likewise ----
        float qa[16], qb[16];
#pragma unroll
        for (int f = 0; f < 16; ++f) { qa[f] = qs[i0r][f]; qb[f] = qs[i1r][f]; }
        float num0[4] = {0, 0, 0, 0}, num1[4] = {0, 0, 0, 0};
        float den0 = 0.f, den1 = 0.f;

        for (int j = 0; j <= i1r; ++j) {
            float s0 = 0.f, s1 = 0.f;
#pragma unroll
            for (int f = 0; f < 16; ++f) { float kf_ = ks[j][f]; s0 += qa[f] * kf_; s1 += qb[f] * kf_; }
            s0 *= 0.25f; s1 *= 0.25f;
            float a0 = 1.f + s0 + 0.5f * s0 * s0;
            float a1 = 1.f + s1 + 0.5f * s1 * s1;
            if (j > i0r) a0 = 0.f;
            den0 += a0; den1 += a1;
            const float4 vj = *(const float4*)&vs[j][eg * 4];
            num0[0] += a0 * vj.x; num0[1] += a0 * vj.y; num0[2] += a0 * vj.z; num0[3] += a0 * vj.w;
            num1[0] += a1 * vj.x; num1[1] += a1 * vj.y; num1[2] += a1 * vj.z; num1[3] += a1 * vj.w;
        }
        // cross-chunk: d = 0
        {
            float zd = zs[0];
            const float4 Sd = *(const float4*)&Ss[0][eg * 4];
            den0 += zd; den1 += zd;
            num0[0] += Sd.x; num0[1] += Sd.y; num0[2] += Sd.z; num0[3] += Sd.w;
            num1[0] += Sd.x; num1[1] += Sd.y; num1[2] += Sd.z; num1[3] += Sd.w;
        }
        // linear features d = 1..16
#pragma unroll
        for (int f = 0; f < 16; ++f) {
            float c0 = qa[f] * 0.5f, c1 = qb[f] * 0.5f;
            float zd = zs[1 + f];
            const float4 Sd = *(const float4*)&Ss[1 + f][eg * 4];
            den0 += c0 * zd; den1 += c1 * zd;
            num0[0] += c0 * Sd.x; num0[1] += c0 * Sd.y; num0[2] += c0 * Sd.z; num0[3] += c0 * Sd.w;
            num1[0] += c1 * Sd.x; num1[1] += c1 * Sd.y; num1[2] += c1 * Sd.z; num1[3] += c1 * Sd.w;
        }
        // quadratic features d = 17 + f1*16 + f2
        for (int fa = 0; fa < 16; ++fa) {
            float c0a = qa[fa] * INV_R2RD, c1a = qb[fa] * INV_R2RD;
#pragma unroll
            for (int fb = 0; fb < 16; ++fb) {
                int d = 17 + fa * 16 + fb;
                float q0 = c0a * qa[fb], q1 = c1a * qb[fb];
                float zd = zs[d];
                const float4 Sd = *(const float4*)&Ss[d][eg * 4];
                den0 += q0 * zd; den1 += q1 * zd;
                num0[0] += q0 * Sd.x; num0[1] += q0 * Sd.y; num0[2] += q0 * Sd.z; num0[3] += q0 * Sd.w;
                num1[0] += q1 * Sd.x; num1[1] += q1 * Sd.y; num1[2] += q1 * Sd.z; num1[3] += q1 * Sd.w;
            }
        }
        {
            float r0 = den0 + EPS, r1 = den1 + EPS;
            float4 o0 = { num0[0] / r0, num0[1] / r0, num0[2] / r0, num0[3] / r0 };
            float4 o1 = { num1[0] / r1, num1[1] / r1, num1[2] / r1, num1[3] / r1 };
            *(float4*)(yg + (rowbase + i0r) * 1024 + h * 64 + es * 16 + eg * 4) = o0;
            *(float4*)(yg + (rowbase + i1r) * 1024 + h * 64 + es * 16 + eg * 4) = o1;
        }
        __syncthreads();   // stage-2 reads of Ss/zs done before updates

        // ---- stage 3: S += kf^T @ v,  z += sum_j kf_j ----
        // quadratic rows: thread owns (f1, 4 f2, 4 e)
        {
            float acc[4][4] = {};
            for (int j = 0; j < CHUNK; ++j) {
                float k1 = ks[j][f1] * INV_R2RD;
                const float4 k2 = *(const float4*)&ks[j][f2g * 4];
                const float4 vj = *(const float4*)&vs[j][eg * 4];
                float kf0 = k1 * k2.x, kf1 = k1 * k2.y, kf2 = k1 * k2.z, kf3 = k1 * k2.w;
                acc[0][0] += kf0 * vj.x; acc[0][1] += kf0 * vj.y; acc[0][2] += kf0 * vj.z; acc[0][3] += kf0 * vj.w;
                acc[1][0] += kf1 * vj.x; acc[1][1] += kf1 * vj.y; acc[1][2] += kf1 * vj.z; acc[1][3] += kf1 * vj.w;
                acc[2][0] += kf2 * vj.x; acc[2][1] += kf2 * vj.y; acc[2][2] += kf2 * vj.z; acc[2][3] += kf2 * vj.w;
                acc[3][0] += kf3 * vj.x; acc[3][1] += kf3 * vj.y; acc[3][2] += kf3 * vj.z; acc[3][3] += kf3 * vj.w;
            }
#pragma unroll
            for (int u = 0; u < 4; ++u) {
                int d = 17 + f1 * 16 + f2g * 4 + u;
                float4* p = (float4*)&Ss[d][eg * 4];
                float4 cur = *p;
                cur.x += acc[u][0]; cur.y += acc[u][1]; cur.z += acc[u][2]; cur.w += acc[u][3];
                *p = cur;
            }
        }
        // const + linear rows d = 0..16 (68 threads)
        if (tid < 68) {
            int d = tid >> 2, eg2 = tid & 3;
            float a0 = 0.f, a1 = 0.f, a2 = 0.f, a3 = 0.f;
            for (int j = 0; j < CHUNK; ++j) {
                float kf = (d == 0) ? 1.f : ks[j][d - 1] * 0.5f;
                const float4 vj = *(const float4*)&vs[j][eg2 * 4];
                a0 += kf * vj.x; a1 += kf * vj.y; a2 += kf * vj.z; a3 += kf * vj.w;
            }
            float4* p = (float4*)&Ss[d][eg2 * 4];
            float4 cur = *p;
            cur.x += a0; cur.y += a1; cur.z += a2; cur.w += a3;
            *p = cur;
        }
        // z update (each d owned by one thread)
        for (int d = tid; d < DE; d += 256) {
            float za = 0.f;
            if (d == 0) {
                za = (float)CHUNK;
            } else if (d < 17) {
                for (int j = 0; j < CHUNK; ++j) za += ks[j][d - 1];
                za *= 0.5f;
            } else {
                int fa = (d - 17) >> 4, fb = (d - 17) & 15;
                for (int j = 0; j < CHUNK; ++j) za += ks[j][fa] * ks[j][fb];
                za *= INV_R2RD;
            }
            zs[d] += za;
        }
    }
}

// ---------------------------------------------------------------------------
extern "C" void kernel_launch(void* const* d_in, const int* in_sizes, int n_in,
                              void* d_out, int out_size, void* d_ws, size_t ws_size,
                              hipStream_t stream)
{
    (void)in_sizes; (void)n_in; (void)out_size; (void)ws_size;
    const float* hs = (const float*)d_in[0];   // (B, L, 1024)
    const float* Wq = (const float*)d_in[1];   // (256, 1024)
    const float* Wk = (const float*)d_in[2];   // (256, 1024)
    const float* Wv = (const float*)d_in[3];   // (1024, 1024)
    const float* Wo = (const float*)d_in[4];   // (1024, 1024)
    float* out = (float*)d_out;                // (B, L, 1024)

    const int M = BB * LL;                     // 8192
    float* qbuf = (float*)d_ws;                // M*256
    float* kbuf = qbuf + (size_t)M * 256;      // M*256
    float* vbuf = kbuf + (size_t)M * 256;      // M*1024
    float* ybuf = vbuf + (size_t)M * 1024;     // M*1024   (total 80 MB)

    dim3 blk(256);
    gemm_abt<<<dim3(256 / 64,  M / 64), blk, 0, stream>>>(hs, Wq, qbuf, M, 256,  DM);
    gemm_abt<<<dim3(256 / 64,  M / 64), blk, 0, stream>>>(hs, Wk, kbuf, M, 256,  DM);
    gemm_abt<<<dim3(1024 / 64, M / 64), blk, 0, stream>>>(hs, Wv, vbuf, M, 1024, DM);
    attn_kernel<<<dim3(256), blk, 0, stream>>>(qbuf, kbuf, vbuf, ybuf);
    gemm_abt<<<dim3(1024 / 64, M / 64), blk, 0, stream>>>(ybuf, Wo, out, M, 1024, DM);
}

// Round 2
// 551.798 us; speedup vs baseline: 2.2236x; 2.2236x over previous
//
#include <hip/hip_runtime.h>
#include <hip/hip_bf16.h>

#define BB 4
#define LL 2048
#define DM 1024
#define NH 16
#define FEAT 16
#define HD 64
#define CHUNK 128
#define NCHUNK 16
#define DE 273                // 1 + 16 + 256
#define EPS 1e-12f
#define INV_R2RD 0.17677669529663688f   // 1/(4*sqrt(2))

typedef short bf16x8_t __attribute__((ext_vector_type(8)));
typedef float f32x4_t  __attribute__((ext_vector_type(4)));

__device__ __forceinline__ float b2f(unsigned short u) {
    union { unsigned int i; float f; } x; x.i = ((unsigned int)u) << 16; return x.f;
}
__device__ __forceinline__ unsigned short f2b(float f) {
    __hip_bfloat16 h = __float2bfloat16(f);
    return *reinterpret_cast<unsigned short*>(&h);
}
__device__ __forceinline__ void unpack8(uint4 r, float* o) {
    o[0] = __uint_as_float(r.x << 16); o[1] = __uint_as_float(r.x & 0xffff0000u);
    o[2] = __uint_as_float(r.y << 16); o[3] = __uint_as_float(r.y & 0xffff0000u);
    o[4] = __uint_as_float(r.z << 16); o[5] = __uint_as_float(r.z & 0xffff0000u);
    o[6] = __uint_as_float(r.w << 16); o[7] = __uint_as_float(r.w & 0xffff0000u);
}

// ---------------------------------------------------------------------------
// fp32 -> bf16 cast (vectorized)
// ---------------------------------------------------------------------------
__global__ __launch_bounds__(256)
void cast_f32_bf16(const float* __restrict__ src, unsigned short* __restrict__ dst, int n) {
    int i = (blockIdx.x * 256 + threadIdx.x) * 4;
    if (i >= n) return;
    float4 v = *(const float4*)(src + i);
    ushort4 o; o.x = f2b(v.x); o.y = f2b(v.y); o.z = f2b(v.z); o.w = f2b(v.w);
    *(ushort4*)(dst + i) = o;
}

// ---------------------------------------------------------------------------
// bf16 MFMA GEMM: C[M,N] = A[M,K] @ Bw[N,K]^T, fp32 accumulate.
// 128x128 tile, BK=32, 256 threads (4 waves, 2x2 of 64x64), 16x16x32 MFMA,
// global_load_lds width-16 staging (m97 recipe).
// ---------------------------------------------------------------------------
template <typename OutT>
__global__ __launch_bounds__(256)
void gemm_bf16(const unsigned short* __restrict__ A, const unsigned short* __restrict__ Bw,
               OutT* __restrict__ C, int M, int N, int K)
{
    __shared__ unsigned short As[128 * 32];
    __shared__ unsigned short Bs[128 * 32];
    const int tid  = threadIdx.x;
    const int wave = tid >> 6, lane = tid & 63;
    const int m0 = blockIdx.y * 128, n0 = blockIdx.x * 128;
    const int wm = (wave >> 1) * 64, wn = (wave & 1) * 64;
    const int srow = tid >> 2;     // staging row 0..63 (+64 on pass 1)
    const int skc  = tid & 3;      // staging 16B chunk within 64B row
    const int ml = lane & 15, qq = lane >> 4;

    f32x4_t acc[4][4];
#pragma unroll
    for (int i = 0; i < 4; ++i)
#pragma unroll
        for (int j = 0; j < 4; ++j) acc[i][j] = (f32x4_t){0.f, 0.f, 0.f, 0.f};

    for (int k0 = 0; k0 < K; k0 += 32) {
#pragma unroll
        for (int p = 0; p < 2; ++p) {
            const int row = p * 64 + srow;
            const unsigned short* ga = A  + (size_t)(m0 + row) * K + k0 + skc * 8;
            const unsigned short* gb = Bw + (size_t)(n0 + row) * K + k0 + skc * 8;
            // wave-uniform LDS base; HW scatters lane*16B (contiguous layout)
            unsigned short* la = As + (size_t)(p * 64 + wave * 16) * 32;
            unsigned short* lb = Bs + (size_t)(p * 64 + wave * 16) * 32;
            __builtin_amdgcn_global_load_lds((const __attribute__((address_space(1))) void*)ga,
                                             (__attribute__((address_space(3))) void*)la, 16, 0, 0);
            __builtin_amdgcn_global_load_lds((const __attribute__((address_space(1))) void*)gb,
                                             (__attribute__((address_space(3))) void*)lb, 16, 0, 0);
        }
        __syncthreads();
        bf16x8_t af[4], bfr[4];
#pragma unroll
        for (int i = 0; i < 4; ++i) {
            af[i]  = *(const bf16x8_t*)(As + (wm + i * 16 + ml) * 32 + qq * 8);
            bfr[i] = *(const bf16x8_t*)(Bs + (wn + i * 16 + ml) * 32 + qq * 8);
        }
#pragma unroll
        for (int i = 0; i < 4; ++i)
#pragma unroll
            for (int j = 0; j < 4; ++j)
                acc[i][j] = __builtin_amdgcn_mfma_f32_16x16x32_bf16(af[i], bfr[j], acc[i][j], 0, 0, 0);
        __syncthreads();
    }
    // epilogue: D[row=(lane>>4)*4+r][col=lane&15]
#pragma unroll
    for (int i = 0; i < 4; ++i) {
        const int rbase = m0 + wm + i * 16 + qq * 4;
#pragma unroll
        for (int j = 0; j < 4; ++j) {
            const int col = n0 + wn + j * 16 + ml;
#pragma unroll
            for (int r = 0; r < 4; ++r) {
                const float v = acc[i][j][r];
                if constexpr (sizeof(OutT) == 2) {
                    ((unsigned short*)C)[(size_t)(rbase + r) * N + col] = f2b(v);
                } else {
                    ((float*)C)[(size_t)(rbase + r) * N + col] = v;
                }
            }
        }
    }
}

// ---------------------------------------------------------------------------
// Kernel A: per-chunk state contributions. Block = (bh, c, es):
//   S_c[273][16-slice] = kf_c^T @ v_c ; z_c[273] (es==0 blocks only).
// ---------------------------------------------------------------------------
__global__ __launch_bounds__(256)
void state_kernel(const unsigned short* __restrict__ kg, const unsigned short* __restrict__ vg,
                  unsigned short* __restrict__ Sg, float* __restrict__ zg)
{
    __shared__ float ks[CHUNK][16];
    __shared__ float vs[CHUNK][16];
    const int x  = blockIdx.x;
    const int es = x & 3, c = (x >> 2) & 15, bh = x >> 6;
    const int b = bh >> 4, h = bh & 15;
    const int tid = threadIdx.x;
    const size_t rowbase = (size_t)(b * LL + c * CHUNK);

    {
        const int row = tid >> 1, half = tid & 1;
        float t[8];
        uint4 rk = *(const uint4*)(kg + (rowbase + row) * 256 + h * 16 + half * 8);
        unpack8(rk, t);
#pragma unroll
        for (int i = 0; i < 8; ++i) ks[row][half * 8 + i] = t[i];
        uint4 rv = *(const uint4*)(vg + (rowbase + row) * 1024 + h * 64 + es * 16 + half * 8);
        unpack8(rv, t);
#pragma unroll
        for (int i = 0; i < 8; ++i) vs[row][half * 8 + i] = t[i];
    }
    __syncthreads();

    const int f1 = tid >> 4, f2g = (tid >> 2) & 3, eg = tid & 3;
    const size_t Sbase = ((size_t)(bh * 16 + c)) * DE * 64 + es * 16;

    // quadratic rows d = 17 + f1*16 + f2
    {
        float acc[4][4] = {};
        for (int j = 0; j < CHUNK; ++j) {
            const float k1 = ks[j][f1] * INV_R2RD;
            const float4 k2 = *(const float4*)&ks[j][f2g * 4];
            const float4 vj = *(const float4*)&vs[j][eg * 4];
            const float kf0 = k1 * k2.x, kf1 = k1 * k2.y, kf2 = k1 * k2.z, kf3 = k1 * k2.w;
            acc[0][0] += kf0 * vj.x; acc[0][1] += kf0 * vj.y; acc[0][2] += kf0 * vj.z; acc[0][3] += kf0 * vj.w;
            acc[1][0] += kf1 * vj.x; acc[1][1] += kf1 * vj.y; acc[1][2] += kf1 * vj.z; acc[1][3] += kf1 * vj.w;
            acc[2][0] += kf2 * vj.x; acc[2][1] += kf2 * vj.y; acc[2][2] += kf2 * vj.z; acc[2][3] += kf2 * vj.w;
            acc[3][0] += kf3 * vj.x; acc[3][1] += kf3 * vj.y; acc[3][2] += kf3 * vj.z; acc[3][3] += kf3 * vj.w;
        }
#pragma unroll
        for (int u = 0; u < 4; ++u) {
            const int d = 17 + f1 * 16 + f2g * 4 + u;
            ushort4 st;
            st.x = f2b(acc[u][0]); st.y = f2b(acc[u][1]); st.z = f2b(acc[u][2]); st.w = f2b(acc[u][3]);
            *(ushort4*)(Sg + Sbase + (size_t)d * 64 + eg * 4) = st;
        }
    }
    // const + linear rows d = 0..16
    if (tid < 68) {
        const int d = tid >> 2, eg2 = tid & 3;
        float a0 = 0.f, a1 = 0.f, a2 = 0.f, a3 = 0.f;
        for (int j = 0; j < CHUNK; ++j) {
            const float kf = (d == 0) ? 1.f : ks[j][d - 1] * 0.5f;
            const float4 vj = *(const float4*)&vs[j][eg2 * 4];
            a0 += kf * vj.x; a1 += kf * vj.y; a2 += kf * vj.z; a3 += kf * vj.w;
        }
        ushort4 st; st.x = f2b(a0); st.y = f2b(a1); st.z = f2b(a2); st.w = f2b(a3);
        *(ushort4*)(Sg + Sbase + (size_t)d * 64 + eg2 * 4) = st;
    }
    // z contributions (one es-slice writes)
    if (es == 0) {
        for (int d = tid; d < DE; d += 256) {
            float za = 0.f;
            if (d == 0) {
                za = (float)CHUNK;
            } else if (d < 17) {
                for (int j = 0; j < CHUNK; ++j) za += ks[j][d - 1];
                za *= 0.5f;
            } else {
                const int fa = (d - 17) >> 4, fb = (d - 17) & 15;
                for (int j = 0; j < CHUNK; ++j) za += ks[j][fa] * ks[j][fb];
                za *= INV_R2RD;
            }
            zg[(size_t)(bh * 16 + c) * DE + d] = za;
        }
    }
}

// ---------------------------------------------------------------------------
// Kernel B: in-place exclusive prefix scan over the 16 chunks (fp32 accum).
// ---------------------------------------------------------------------------
__global__ __launch_bounds__(256)
void scan_S(unsigned short* __restrict__ Sg) {
    const int bh  = blockIdx.y;
    const int idx = blockIdx.x * 256 + threadIdx.x;
    if (idx >= DE * 64) return;
    const size_t base = (size_t)bh * NCHUNK * (DE * 64) + idx;
    float acc = 0.f;
    for (int c = 0; c < NCHUNK; ++c) {
        unsigned short* p = Sg + base + (size_t)c * (DE * 64);
        const float t = b2f(*p);
        *p = f2b(acc);
        acc += t;
    }
}
__global__ __launch_bounds__(256)
void scan_z(float* __restrict__ zg) {
    const int bh  = blockIdx.y;
    const int idx = blockIdx.x * 256 + threadIdx.x;
    if (idx >= DE) return;
    const size_t base = (size_t)bh * NCHUNK * DE + idx;
    float acc = 0.f;
    for (int c = 0; c < NCHUNK; ++c) {
        float* p = zg + base + (size_t)c * DE;
        const float t = *p;
        *p = acc;
        acc += t;
    }
}

// ---------------------------------------------------------------------------
// Kernel C: outputs. Block = (bh, c, es). Intra-chunk via collapsed score
// a = 1 + s + s^2/2 (s = q.k/4); cross-chunk via staged S_prefix, z_prefix.
// Writes y (bf16) over the v buffer (same rows/cols; LDS-staged first).
// ---------------------------------------------------------------------------
__global__ __launch_bounds__(256)
void out_kernel(const unsigned short* __restrict__ qg, const unsigned short* __restrict__ kg,
                const unsigned short* vg, const unsigned short* __restrict__ Sg,
                const float* __restrict__ zg, unsigned short* yg)
{
    __shared__ float qs[CHUNK][16];
    __shared__ float ks[CHUNK][16];
    __shared__ float vs[CHUNK][16];
    __shared__ float Ss[DE][16];
    __shared__ float zs[DE];

    const int x  = blockIdx.x;
    const int es = x & 3, c = (x >> 2) & 15, bh = x >> 6;
    const int b = bh >> 4, h = bh & 15;
    const int tid = threadIdx.x;
    const size_t rowbase = (size_t)(b * LL + c * CHUNK);

    {
        const int row = tid >> 1, half = tid & 1;
        float t[8];
        uint4 rq = *(const uint4*)(qg + (rowbase + row) * 256 + h * 16 + half * 8);
        unpack8(rq, t);
#pragma unroll
        for (int i = 0; i < 8; ++i) qs[row][half * 8 + i] = t[i];
        uint4 rk = *(const uint4*)(kg + (rowbase + row) * 256 + h * 16 + half * 8);
        unpack8(rk, t);
#pragma unroll
        for (int i = 0; i < 8; ++i) ks[row][half * 8 + i] = t[i];
        uint4 rv = *(const uint4*)(vg + (rowbase + row) * 1024 + h * 64 + es * 16 + half * 8);
        unpack8(rv, t);
#pragma unroll
        for (int i = 0; i < 8; ++i) vs[row][half * 8 + i] = t[i];
    }
    {
        const size_t Sbase = ((size_t)(bh * 16 + c)) * DE * 64 + es * 16;
        for (int idx8 = tid; idx8 < 546; idx8 += 256) {   // 273*16/8
            const int d = idx8 >> 1, half = idx8 & 1;
            float t[8];
            uint4 rs = *(const uint4*)(Sg + Sbase + (size_t)d * 64 + half * 8);
            unpack8(rs, t);
#pragma unroll
            for (int i = 0; i < 8; ++i) Ss[d][half * 8 + i] = t[i];
        }
        const size_t zbase = (size_t)(bh * 16 + c) * DE;
        for (int d = tid; d < DE; d += 256) zs[d] = zg[zbase + d];
    }
    __syncthreads();

    const int it = tid >> 2, eg = tid & 3;
    const int i0r = it * 2, i1r = i0r + 1;
    float qa[16], qb[16];
#pragma unroll
    for (int f = 0; f < 16; ++f) { qa[f] = qs[i0r][f]; qb[f] = qs[i1r][f]; }
    float num0[4] = {0, 0, 0, 0}, num1[4] = {0, 0, 0, 0};
    float den0 = 0.f, den1 = 0.f;

    // intra-chunk (masked)
    for (int j = 0; j <= i1r; ++j) {
        float s0 = 0.f, s1 = 0.f;
#pragma unroll
        for (int f = 0; f < 16; ++f) { const float kf_ = ks[j][f]; s0 += qa[f] * kf_; s1 += qb[f] * kf_; }
        s0 *= 0.25f; s1 *= 0.25f;
        float a0 = 1.f + s0 + 0.5f * s0 * s0;
        float a1 = 1.f + s1 + 0.5f * s1 * s1;
        if (j > i0r) a0 = 0.f;
        den0 += a0; den1 += a1;
        const float4 vj = *(const float4*)&vs[j][eg * 4];
        num0[0] += a0 * vj.x; num0[1] += a0 * vj.y; num0[2] += a0 * vj.z; num0[3] += a0 * vj.w;
        num1[0] += a1 * vj.x; num1[1] += a1 * vj.y; num1[2] += a1 * vj.z; num1[3] += a1 * vj.w;
    }
    // cross-chunk: d=0
    {
        const float zd = zs[0];
        const float4 Sd = *(const float4*)&Ss[0][eg * 4];
        den0 += zd; den1 += zd;
        num0[0] += Sd.x; num0[1] += Sd.y; num0[2] += Sd.z; num0[3] += Sd.w;
        num1[0] += Sd.x; num1[1] += Sd.y; num1[2] += Sd.z; num1[3] += Sd.w;
    }
    // linear features
#pragma unroll
    for (int f = 0; f < 16; ++f) {
        const float c0 = qa[f] * 0.5f, c1 = qb[f] * 0.5f;
        const float zd = zs[1 + f];
        const float4 Sd = *(const float4*)&Ss[1 + f][eg * 4];
        den0 += c0 * zd; den1 += c1 * zd;
        num0[0] += c0 * Sd.x; num0[1] += c0 * Sd.y; num0[2] += c0 * Sd.z; num0[3] += c0 * Sd.w;
        num1[0] += c1 * Sd.x; num1[1] += c1 * Sd.y; num1[2] += c1 * Sd.z; num1[3] += c1 * Sd.w;
    }
    // quadratic features
    for (int fa = 0; fa < 16; ++fa) {
        const float c0a = qa[fa] * INV_R2RD, c1a = qb[fa] * INV_R2RD;
#pragma unroll
        for (int fb = 0; fb < 16; ++fb) {
            const int d = 17 + fa * 16 + fb;
            const float q0 = c0a * qa[fb], q1 = c1a * qb[fb];
            const float zd = zs[d];
            const float4 Sd = *(const float4*)&Ss[d][eg * 4];
            den0 += q0 * zd; den1 += q1 * zd;
            num0[0] += q0 * Sd.x; num0[1] += q0 * Sd.y; num0[2] += q0 * Sd.z; num0[3] += q0 * Sd.w;
            num1[0] += q1 * Sd.x; num1[1] += q1 * Sd.y; num1[2] += q1 * Sd.z; num1[3] += q1 * Sd.w;
        }
    }
    {
        const float r0 = den0 + EPS, r1 = den1 + EPS;
        ushort4 o0, o1;
        o0.x = f2b(num0[0] / r0); o0.y = f2b(num0[1] / r0); o0.z = f2b(num0[2] / r0); o0.w = f2b(num0[3] / r0);
        o1.x = f2b(num1[0] / r1); o1.y = f2b(num1[1] / r1); o1.z = f2b(num1[2] / r1); o1.w = f2b(num1[3] / r1);
        *(ushort4*)(yg + (rowbase + i0r) * 1024 + h * 64 + es * 16 + eg * 4) = o0;
        *(ushort4*)(yg + (rowbase + i1r) * 1024 + h * 64 + es * 16 + eg * 4) = o1;
    }
}

// ---------------------------------------------------------------------------
extern "C" void kernel_launch(void* const* d_in, const int* in_sizes, int n_in,
                              void* d_out, int out_size, void* d_ws, size_t ws_size,
                              hipStream_t stream)
{
    (void)in_sizes; (void)n_in; (void)out_size; (void)ws_size;
    const float* hs = (const float*)d_in[0];
    const float* Wq = (const float*)d_in[1];
    const float* Wk = (const float*)d_in[2];
    const float* Wv = (const float*)d_in[3];
    const float* Wo = (const float*)d_in[4];
    float* out = (float*)d_out;

    const int M = BB * LL;  // 8192
    char* ws = (char*)d_ws;
    // Region 0 (35,782,656 B): S states; hs_bf16 (16 MB) aliases its start
    // (hs_bf dead before state_kernel writes S).
    unsigned short* Sg    = (unsigned short*)ws;
    unsigned short* hs_bf = (unsigned short*)ws;
    size_t off = 35782656;
    unsigned short* qb    = (unsigned short*)(ws + off); off += 4194304;   // 8192x256 bf16
    unsigned short* kb    = (unsigned short*)(ws + off); off += 4194304;
    unsigned short* vb    = (unsigned short*)(ws + off); off += 16777216;  // 8192x1024 bf16 (v, then y)
    unsigned short* Wq_bf = (unsigned short*)(ws + off); off += 524288;
    unsigned short* Wk_bf = (unsigned short*)(ws + off); off += 524288;
    unsigned short* Wv_bf = (unsigned short*)(ws + off); off += 2097152;
    unsigned short* Wo_bf = (unsigned short*)(ws + off); off += 2097152;
    float*          zg    = (float*)(ws + off);          off += 1118208;   // 64*16*273 fp32

    // casts
    cast_f32_bf16<<<8192, 256, 0, stream>>>(hs, hs_bf, M * DM);
    cast_f32_bf16<<<256,  256, 0, stream>>>(Wq, Wq_bf, 256 * DM);
    cast_f32_bf16<<<256,  256, 0, stream>>>(Wk, Wk_bf, 256 * DM);
    cast_f32_bf16<<<1024, 256, 0, stream>>>(Wv, Wv_bf, DM * DM);
    cast_f32_bf16<<<1024, 256, 0, stream>>>(Wo, Wo_bf, DM * DM);
    // projections (MFMA)
    gemm_bf16<unsigned short><<<dim3(2, 64), 256, 0, stream>>>(hs_bf, Wq_bf, qb, M, 256, DM);
    gemm_bf16<unsigned short><<<dim3(2, 64), 256, 0, stream>>>(hs_bf, Wk_bf, kb, M, 256, DM);
    gemm_bf16<unsigned short><<<dim3(8, 64), 256, 0, stream>>>(hs_bf, Wv_bf, vb, M, 1024, DM);
    // chunk states + exclusive scan
    state_kernel<<<4096, 256, 0, stream>>>(kb, vb, Sg, zg);
    scan_S<<<dim3(69, 64), 256, 0, stream>>>(Sg);
    scan_z<<<dim3(2, 64), 256, 0, stream>>>(zg);
    // outputs (y overwrites v in place, block-local)
    out_kernel<<<4096, 256, 0, stream>>>(qb, kb, vb, Sg, zg, vb);
    // final projection (MFMA, fp32 out)
    gemm_bf16<float><<<dim3(8, 64), 256, 0, stream>>>(vb, Wo_bf, out, M, DM, DM);
}

// Round 3
// 236.203 us; speedup vs baseline: 5.1945x; 2.3361x over previous
//
#include <hip/hip_runtime.h>
#include <hip/hip_bf16.h>

#define BB 4
#define LL 2048
#define DM 1024
#define NH 16
#define FEAT 16
#define HD 64
#define CHUNK 128
#define NCHUNK 16
#define DEP 288               // padded feature dim: [1][q/2 x16][0 x7][qxq/(4sqrt2) x256][0 x8]
#define NEXT 80               // 64 v-cols + 1 ones-col + 15 pad
#define SROW (DEP * NEXT)     // 23040 elems per (bh,c) state slab, layout [e][d] (transposed)
#define EPS 1e-12f
#define INV_R2RD 0.17677669529663688f   // 1/(4*sqrt(2))
#define QKVLD 1536

typedef short bf16x8_t __attribute__((ext_vector_type(8)));
typedef float f32x4_t  __attribute__((ext_vector_type(4)));

__device__ __forceinline__ float b2f(unsigned short u) {
    union { unsigned int i; float f; } x; x.i = ((unsigned int)u) << 16; return x.f;
}
__device__ __forceinline__ unsigned short f2b(float f) {
    __hip_bfloat16 h = __float2bfloat16(f);
    return *reinterpret_cast<unsigned short*>(&h);
}

__global__ __launch_bounds__(256)
void cast_f32_bf16(const float* __restrict__ src, unsigned short* __restrict__ dst, int n) {
    int i = (blockIdx.x * 256 + threadIdx.x) * 4;
    if (i >= n) return;
    float4 v = *(const float4*)(src + i);
    ushort4 o; o.x = f2b(v.x); o.y = f2b(v.y); o.z = f2b(v.z); o.w = f2b(v.w);
    *(ushort4*)(dst + i) = o;
}

// ---------------------------------------------------------------------------
// bf16 MFMA GEMM: C[M,N] = A[M,K] @ Bw[N,K]^T (fp32 acc), strided variants.
// 128x128 tile, BK=32, 256 threads, m97 recipe (global_load_lds width-16).
// ---------------------------------------------------------------------------
template <typename OutT>
__global__ __launch_bounds__(256)
void gemm_bf16(const unsigned short* __restrict__ A, const unsigned short* __restrict__ Bw,
               OutT* __restrict__ C, int M, int N, int K, int lda, int ldb, int ldc)
{
    __shared__ unsigned short As[128 * 32];
    __shared__ unsigned short Bs[128 * 32];
    const int tid  = threadIdx.x;
    const int wave = tid >> 6, lane = tid & 63;
    const int m0 = blockIdx.y * 128, n0 = blockIdx.x * 128;
    const int wm = (wave >> 1) * 64, wn = (wave & 1) * 64;
    const int srow = tid >> 2;
    const int skc  = tid & 3;
    const int ml = lane & 15, qq = lane >> 4;

    f32x4_t acc[4][4];
#pragma unroll
    for (int i = 0; i < 4; ++i)
#pragma unroll
        for (int j = 0; j < 4; ++j) acc[i][j] = (f32x4_t){0.f, 0.f, 0.f, 0.f};

    for (int k0 = 0; k0 < K; k0 += 32) {
#pragma unroll
        for (int p = 0; p < 2; ++p) {
            const int row = p * 64 + srow;
            const unsigned short* ga = A  + (size_t)(m0 + row) * lda + k0 + skc * 8;
            const unsigned short* gb = Bw + (size_t)(n0 + row) * ldb + k0 + skc * 8;
            unsigned short* la = As + (size_t)(p * 64 + wave * 16) * 32;
            unsigned short* lb = Bs + (size_t)(p * 64 + wave * 16) * 32;
            __builtin_amdgcn_global_load_lds((const __attribute__((address_space(1))) void*)ga,
                                             (__attribute__((address_space(3))) void*)la, 16, 0, 0);
            __builtin_amdgcn_global_load_lds((const __attribute__((address_space(1))) void*)gb,
                                             (__attribute__((address_space(3))) void*)lb, 16, 0, 0);
        }
        __syncthreads();
        bf16x8_t af[4], bfr[4];
#pragma unroll
        for (int i = 0; i < 4; ++i) {
            af[i]  = *(const bf16x8_t*)(As + (wm + i * 16 + ml) * 32 + qq * 8);
            bfr[i] = *(const bf16x8_t*)(Bs + (wn + i * 16 + ml) * 32 + qq * 8);
        }
#pragma unroll
        for (int i = 0; i < 4; ++i)
#pragma unroll
            for (int j = 0; j < 4; ++j)
                acc[i][j] = __builtin_amdgcn_mfma_f32_16x16x32_bf16(af[i], bfr[j], acc[i][j], 0, 0, 0);
        __syncthreads();
    }
#pragma unroll
    for (int i = 0; i < 4; ++i) {
        const int rbase = m0 + wm + i * 16 + qq * 4;
#pragma unroll
        for (int j = 0; j < 4; ++j) {
            const int col = n0 + wn + j * 16 + ml;
#pragma unroll
            for (int r = 0; r < 4; ++r) {
                const float v = acc[i][j][r];
                if constexpr (sizeof(OutT) == 2) {
                    ((unsigned short*)C)[(size_t)(rbase + r) * ldc + col] = f2b(v);
                } else {
                    ((float*)C)[(size_t)(rbase + r) * ldc + col] = v;
                }
            }
        }
    }
}

// ---------------------------------------------------------------------------
// state_kernel: per (bh,c) computes S_c^T stored [e 0..79][d 0..287] bf16.
// S_c = Kf^T @ V_ext (MFMA); row e=64 of V_ext = ones -> col 64 of S = z.
// ---------------------------------------------------------------------------
__global__ __launch_bounds__(256)
void state_kernel(const unsigned short* __restrict__ qkv, unsigned short* __restrict__ STg)
{
    __shared__ unsigned short KT[16 * 136];   // K transposed [f][j], padded
    __shared__ unsigned short VT[80 * 136];   // V_ext transposed [e][j], padded

    const int x = blockIdx.x;
    const int c = x & 15, bh = x >> 4;
    const int b = bh >> 4, h = bh & 15;
    const int tid = threadIdx.x;
    const int wave = tid >> 6, lane = tid & 63;
    const int ml = lane & 15, kg8 = (lane >> 4) * 8;
    const size_t rowbase = (size_t)(b * LL + c * CHUNK);
    const size_t Sbase = (size_t)x * SROW;

    {
        const int row = tid >> 1, half = tid & 1;
        // K -> KT
        uint4 kv = *(const uint4*)(qkv + (rowbase + row) * QKVLD + 256 + h * 16 + half * 8);
        const unsigned short* kp = (const unsigned short*)&kv;
#pragma unroll
        for (int i = 0; i < 8; ++i) KT[(half * 8 + i) * 136 + row] = kp[i];
        // V -> VT
#pragma unroll
        for (int cc = 0; cc < 4; ++cc) {
            uint4 vv = *(const uint4*)(qkv + (rowbase + row) * QKVLD + 512 + h * 64 + half * 32 + cc * 8);
            const unsigned short* vp = (const unsigned short*)&vv;
#pragma unroll
            for (int i = 0; i < 8; ++i) VT[(half * 32 + cc * 8 + i) * 136 + row] = vp[i];
        }
        if (half == 0) {
            VT[64 * 136 + row] = 0x3F80;   // ones column
        } else {
#pragma unroll
            for (int e = 65; e < 80; ++e) VT[e * 136 + row] = 0;
        }
    }
    __syncthreads();

    // B-fragments (V_ext^T), shared across all m-tiles of this wave
    bf16x8_t bfr[5][4];
#pragma unroll
    for (int nt = 0; nt < 5; ++nt)
#pragma unroll
        for (int ks = 0; ks < 4; ++ks)
            bfr[nt][ks] = *(const bf16x8_t*)&VT[(nt * 16 + ml) * 136 + ks * 32 + kg8];

    for (int mt = wave; mt < 18; mt += 4) {
        const int d = mt * 16 + ml;
        bf16x8_t af[4];
#pragma unroll
        for (int ks = 0; ks < 4; ++ks) {
            const int jb = ks * 32 + kg8;
            unsigned short o[8];
            if (d >= 24 && d < 280) {
                const int e = d - 24, a = e >> 4, bq = e & 15;
                bf16x8_t ka = *(const bf16x8_t*)&KT[a  * 136 + jb];
                bf16x8_t kb = *(const bf16x8_t*)&KT[bq * 136 + jb];
#pragma unroll
                for (int j = 0; j < 8; ++j)
                    o[j] = f2b(b2f((unsigned short)ka[j]) * b2f((unsigned short)kb[j]) * INV_R2RD);
            } else if (d == 0) {
#pragma unroll
                for (int j = 0; j < 8; ++j) o[j] = 0x3F80;
            } else if (d <= 16) {
                bf16x8_t kx = *(const bf16x8_t*)&KT[(d - 1) * 136 + jb];
#pragma unroll
                for (int j = 0; j < 8; ++j) o[j] = f2b(b2f((unsigned short)kx[j]) * 0.5f);
            } else {
#pragma unroll
                for (int j = 0; j < 8; ++j) o[j] = 0;
            }
            af[ks] = *(const bf16x8_t*)o;
        }
        f32x4_t acc[5];
#pragma unroll
        for (int nt = 0; nt < 5; ++nt) acc[nt] = (f32x4_t){0.f, 0.f, 0.f, 0.f};
#pragma unroll
        for (int nt = 0; nt < 5; ++nt)
#pragma unroll
            for (int ks = 0; ks < 4; ++ks)
                acc[nt] = __builtin_amdgcn_mfma_f32_16x16x32_bf16(af[ks], bfr[nt][ks], acc[nt], 0, 0, 0);
        // store: C row = d (feature), col = e; transposed global ST[e][d]
#pragma unroll
        for (int nt = 0; nt < 5; ++nt) {
            ushort4 pk;
            pk.x = f2b(acc[nt][0]); pk.y = f2b(acc[nt][1]);
            pk.z = f2b(acc[nt][2]); pk.w = f2b(acc[nt][3]);
            *(ushort4*)(STg + Sbase + (size_t)(nt * 16 + ml) * DEP + mt * 16 + (lane >> 4) * 4) = pk;
        }
    }
}

// ---------------------------------------------------------------------------
// scan: exclusive prefix over the 16 chunks, elementwise on [80][288] slabs.
// ---------------------------------------------------------------------------
__global__ __launch_bounds__(256)
void scan_S(unsigned short* __restrict__ STg) {
    const int bh  = blockIdx.y;
    const int idx = blockIdx.x * 256 + threadIdx.x;   // 0..23039
    const size_t base = (size_t)bh * NCHUNK * SROW + idx;
    float acc = 0.f;
    for (int c = 0; c < NCHUNK; ++c) {
        unsigned short* p = STg + base + (size_t)c * SROW;
        const float t = b2f(*p);
        *p = f2b(acc);
        acc += t;
    }
}

// ---------------------------------------------------------------------------
// out_kernel: per (bh,c), 256 threads / 4 waves.
// Phase 1: A = poly(Q K^T / 4) masked (MFMA K=32), staged bf16 in LDS.
// Phase 2: Y_ext = A @ V_ext + Qf @ S_ext (MFMA); col 64 = den.
// y = num/den written bf16 in-place over the v columns of qkv.
// LDS (ushort units): Qsmall[128*16]@0 | As[128*136]@2048 | R@19456 (10880):
//   R holds Qpad[128*40]+Ks[128*40] (phase1), then VT[80*136], then STbuf[80*40].
// ---------------------------------------------------------------------------
#define OFF_QS 0
#define OFF_A  2048
#define OFF_R  19456
#define OFF_KS (OFF_R + 5120)

__global__ __launch_bounds__(256)
void out_kernel(const unsigned short* __restrict__ qkv_ro, const unsigned short* __restrict__ STg,
                unsigned short* __restrict__ qkv_w)
{
    __shared__ unsigned short smem[30336];   // 60672 B

    const int x = blockIdx.x;
    const int c = x & 15, bh = x >> 4;
    const int b = bh >> 4, h = bh & 15;
    const int tid = threadIdx.x;
    const int w = tid >> 6, lane = tid & 63;
    const int ml = lane & 15, quad = lane >> 4, kg8 = quad * 8;
    const size_t rowbase = (size_t)(b * LL + c * CHUNK);
    const size_t Sbase = (size_t)x * SROW;

    // ---- load Q (small + padded) and K (padded) ----
    {
        const int row = tid >> 1, half = tid & 1;
        uint4 qv = *(const uint4*)(qkv_ro + (rowbase + row) * QKVLD + h * 16 + half * 8);
        *(uint4*)&smem[OFF_QS + row * 16 + half * 8] = qv;
        *(uint4*)&smem[OFF_R + row * 40 + half * 8] = qv;
        *(uint4*)&smem[OFF_R + row * 40 + 16 + half * 8] = (uint4){0, 0, 0, 0};
        uint4 kv = *(const uint4*)(qkv_ro + (rowbase + row) * QKVLD + 256 + h * 16 + half * 8);
        *(uint4*)&smem[OFF_KS + row * 40 + half * 8] = kv;
        *(uint4*)&smem[OFF_KS + row * 40 + 16 + half * 8] = (uint4){0, 0, 0, 0};
    }
    __syncthreads();

    // ---- phase 1: scores ----
    {
        bf16x8_t q0 = *(const bf16x8_t*)&smem[OFF_R + (w * 32 + ml) * 40 + kg8];
        bf16x8_t q1 = *(const bf16x8_t*)&smem[OFF_R + (w * 32 + 16 + ml) * 40 + kg8];
#pragma unroll
        for (int nt = 0; nt < 8; ++nt) {
            bf16x8_t kf = *(const bf16x8_t*)&smem[OFF_KS + (nt * 16 + ml) * 40 + kg8];
            f32x4_t a0 = __builtin_amdgcn_mfma_f32_16x16x32_bf16(q0, kf, (f32x4_t){0,0,0,0}, 0, 0, 0);
            f32x4_t a1 = __builtin_amdgcn_mfma_f32_16x16x32_bf16(q1, kf, (f32x4_t){0,0,0,0}, 0, 0, 0);
            const int j = nt * 16 + ml;
#pragma unroll
            for (int r = 0; r < 4; ++r) {
                int i0 = w * 32 + quad * 4 + r;
                float s0 = a0[r] * 0.25f;
                float v0 = (j <= i0) ? (1.f + s0 + 0.5f * s0 * s0) : 0.f;
                smem[OFF_A + i0 * 136 + j] = f2b(v0);
                int i1 = i0 + 16;
                float s1 = a1[r] * 0.25f;
                float v1 = (j <= i1) ? (1.f + s1 + 0.5f * s1 * s1) : 0.f;
                smem[OFF_A + i1 * 136 + j] = f2b(v1);
            }
        }
    }
    __syncthreads();

    // ---- load VT over R ----
    {
        const int row = tid >> 1, half = tid & 1;
#pragma unroll
        for (int cc = 0; cc < 4; ++cc) {
            uint4 vv = *(const uint4*)(qkv_ro + (rowbase + row) * QKVLD + 512 + h * 64 + half * 32 + cc * 8);
            const unsigned short* vp = (const unsigned short*)&vv;
#pragma unroll
            for (int i = 0; i < 8; ++i) smem[OFF_R + (half * 32 + cc * 8 + i) * 136 + row] = vp[i];
        }
        if (half == 0) {
            smem[OFF_R + 64 * 136 + row] = 0x3F80;
        } else {
#pragma unroll
            for (int e = 65; e < 80; ++e) smem[OFF_R + e * 136 + row] = 0;
        }
    }
    // q f32 registers for Qf build (rows of this wave's two m-tiles)
    const int r0 = w * 32 + ml, r1 = r0 + 16;
    float qA[16], qB[16];
    {
        bf16x8_t t0 = *(const bf16x8_t*)&smem[OFF_QS + r0 * 16];
        bf16x8_t t1 = *(const bf16x8_t*)&smem[OFF_QS + r0 * 16 + 8];
        bf16x8_t t2 = *(const bf16x8_t*)&smem[OFF_QS + r1 * 16];
        bf16x8_t t3 = *(const bf16x8_t*)&smem[OFF_QS + r1 * 16 + 8];
#pragma unroll
        for (int i = 0; i < 8; ++i) {
            qA[i] = b2f((unsigned short)t0[i]); qA[8 + i] = b2f((unsigned short)t1[i]);
            qB[i] = b2f((unsigned short)t2[i]); qB[8 + i] = b2f((unsigned short)t3[i]);
        }
    }
    __syncthreads();

    f32x4_t acc[2][5];
#pragma unroll
    for (int mt = 0; mt < 2; ++mt)
#pragma unroll
        for (int nt = 0; nt < 5; ++nt) acc[mt][nt] = (f32x4_t){0.f, 0.f, 0.f, 0.f};

    // ---- phase 2a: A @ V_ext ----
#pragma unroll
    for (int ks = 0; ks < 4; ++ks) {
        bf16x8_t af0 = *(const bf16x8_t*)&smem[OFF_A + (w * 32 + ml) * 136 + ks * 32 + kg8];
        bf16x8_t af1 = *(const bf16x8_t*)&smem[OFF_A + (w * 32 + 16 + ml) * 136 + ks * 32 + kg8];
#pragma unroll
        for (int nt = 0; nt < 5; ++nt) {
            bf16x8_t bv = *(const bf16x8_t*)&smem[OFF_R + (nt * 16 + ml) * 136 + ks * 32 + kg8];
            acc[0][nt] = __builtin_amdgcn_mfma_f32_16x16x32_bf16(af0, bv, acc[0][nt], 0, 0, 0);
            acc[1][nt] = __builtin_amdgcn_mfma_f32_16x16x32_bf16(af1, bv, acc[1][nt], 0, 0, 0);
        }
    }

    // ---- phase 2b: Qf @ S_ext, streaming 32-wide d-slices of ST ----
    const unsigned short* qrow0 = &smem[OFF_QS + r0 * 16];
    const unsigned short* qrow1 = &smem[OFF_QS + r1 * 16];
    for (int kq = 0; kq < 9; ++kq) {
        __syncthreads();   // prior reads of R done (VT at kq=0, STbuf after)
        for (int idx = tid; idx < 320; idx += 256) {
            const int e = idx >> 2, c4 = idx & 3;
            uint4 sv = *(const uint4*)(STg + Sbase + (size_t)e * DEP + kq * 32 + c4 * 8);
            *(uint4*)&smem[OFF_R + e * 40 + c4 * 8] = sv;
        }
        __syncthreads();

        bf16x8_t qf[2];
#pragma unroll
        for (int mt = 0; mt < 2; ++mt) {
            const float* q = (mt == 0) ? qA : qB;
            const unsigned short* qrow = (mt == 0) ? qrow0 : qrow1;
            const int d0 = kq * 32 + kg8;
            unsigned short o[8];
            if (d0 >= 24 && d0 < 280) {
                const int e0 = d0 - 24;
                const float qa = b2f(qrow[e0 >> 4]) * INV_R2RD;
                if ((e0 & 15) == 0) {
#pragma unroll
                    for (int j = 0; j < 8; ++j) o[j] = f2b(qa * q[j]);
                } else {
#pragma unroll
                    for (int j = 0; j < 8; ++j) o[j] = f2b(qa * q[8 + j]);
                }
            } else if (d0 == 0) {
                o[0] = 0x3F80;
#pragma unroll
                for (int j = 1; j < 8; ++j) o[j] = f2b(q[j - 1] * 0.5f);
            } else if (d0 == 8) {
#pragma unroll
                for (int j = 0; j < 8; ++j) o[j] = f2b(q[7 + j] * 0.5f);
            } else if (d0 == 16) {
                o[0] = f2b(q[15] * 0.5f);
#pragma unroll
                for (int j = 1; j < 8; ++j) o[j] = 0;
            } else {
#pragma unroll
                for (int j = 0; j < 8; ++j) o[j] = 0;
            }
            qf[mt] = *(const bf16x8_t*)o;
        }
#pragma unroll
        for (int nt = 0; nt < 5; ++nt) {
            bf16x8_t bs = *(const bf16x8_t*)&smem[OFF_R + (nt * 16 + ml) * 40 + kg8];
            acc[0][nt] = __builtin_amdgcn_mfma_f32_16x16x32_bf16(qf[0], bs, acc[0][nt], 0, 0, 0);
            acc[1][nt] = __builtin_amdgcn_mfma_f32_16x16x32_bf16(qf[1], bs, acc[1][nt], 0, 0, 0);
        }
    }

    // ---- epilogue: y = num / (den + eps), den = col 64 (tile 4, ml==0 lanes) ----
#pragma unroll
    for (int mt = 0; mt < 2; ++mt) {
        float den[4];
#pragma unroll
        for (int r = 0; r < 4; ++r) den[r] = __shfl(acc[mt][4][r], lane & 48);
#pragma unroll
        for (int r = 0; r < 4; ++r) {
            const size_t grow = rowbase + w * 32 + mt * 16 + quad * 4 + r;
            const float rc = 1.f / (den[r] + EPS);
#pragma unroll
            for (int nt = 0; nt < 4; ++nt)
                qkv_w[grow * QKVLD + 512 + h * 64 + nt * 16 + ml] = f2b(acc[mt][nt][r] * rc);
        }
    }
}

// ---------------------------------------------------------------------------
extern "C" void kernel_launch(void* const* d_in, const int* in_sizes, int n_in,
                              void* d_out, int out_size, void* d_ws, size_t ws_size,
                              hipStream_t stream)
{
    (void)in_sizes; (void)n_in; (void)out_size; (void)ws_size;
    const float* hs = (const float*)d_in[0];
    const float* Wq = (const float*)d_in[1];
    const float* Wk = (const float*)d_in[2];
    const float* Wv = (const float*)d_in[3];
    const float* Wo = (const float*)d_in[4];
    float* out = (float*)d_out;

    const int M = BB * LL;  // 8192
    char* ws = (char*)d_ws;
    // S region (47,185,920 B) at 0; hs_bf (16 MB) aliases its start (dead
    // before state_kernel writes S).
    unsigned short* STg   = (unsigned short*)ws;
    unsigned short* hs_bf = (unsigned short*)ws;
    size_t off = 47185920;
    unsigned short* qkv   = (unsigned short*)(ws + off); off += 25165824;  // 8192x1536
    unsigned short* Wqkv  = (unsigned short*)(ws + off); off += 3145728;   // 1536x1024
    unsigned short* Wo_bf = (unsigned short*)(ws + off); off += 2097152;   // total 77.6 MB

    cast_f32_bf16<<<8192, 256, 0, stream>>>(hs, hs_bf, M * DM);
    cast_f32_bf16<<<256,  256, 0, stream>>>(Wq, Wqkv, 256 * DM);
    cast_f32_bf16<<<256,  256, 0, stream>>>(Wk, Wqkv + 256 * DM, 256 * DM);
    cast_f32_bf16<<<1024, 256, 0, stream>>>(Wv, Wqkv + 512 * DM, DM * DM);
    cast_f32_bf16<<<1024, 256, 0, stream>>>(Wo, Wo_bf, DM * DM);

    gemm_bf16<unsigned short><<<dim3(12, 64), 256, 0, stream>>>(hs_bf, Wqkv, qkv,
                                                                M, 1536, DM, DM, DM, QKVLD);
    state_kernel<<<1024, 256, 0, stream>>>(qkv, STg);
    scan_S<<<dim3(90, 64), 256, 0, stream>>>(STg);
    out_kernel<<<1024, 256, 0, stream>>>(qkv, STg, qkv);   // y in-place over v cols
    gemm_bf16<float><<<dim3(8, 64), 256, 0, stream>>>(qkv + 512, Wo_bf, out,
                                                      M, DM, DM, QKVLD, DM, DM);
}

// Round 4
// 217.456 us; speedup vs baseline: 5.6423x; 1.0862x over previous
//
#include <hip/hip_runtime.h>
#include <hip/hip_bf16.h>

#define BB 4
#define LL 2048
#define DM 1024
#define NH 16
#define FEAT 16
#define HD 64
#define CHUNK 128
#define NCHUNK 16
#define NEXT 80               // 64 v-cols + 1 ones-col + 15 pad
#define SROW 23040            // 18 dtiles x 80 e x 16 d = per-(bh,c) slab elems
#define EPS 1e-12f
#define INV_R2RD 0.17677669529663688f   // 1/(4*sqrt(2))
#define QKVLD 1536

typedef short bf16x8_t __attribute__((ext_vector_type(8)));
typedef float f32x4_t  __attribute__((ext_vector_type(4)));

__device__ __forceinline__ float b2f(unsigned short u) {
    union { unsigned int i; float f; } x; x.i = ((unsigned int)u) << 16; return x.f;
}
__device__ __forceinline__ unsigned short f2b(float f) {
    __hip_bfloat16 h = __float2bfloat16(f);
    return *reinterpret_cast<unsigned short*>(&h);
}

// ---------------------------------------------------------------------------
// One kernel for all fp32->bf16 casts (5 segments, compile-time boundaries).
// ---------------------------------------------------------------------------
__global__ __launch_bounds__(256)
void cast_all(const float* __restrict__ hs, const float* __restrict__ wq,
              const float* __restrict__ wk, const float* __restrict__ wv,
              const float* __restrict__ wo, unsigned short* __restrict__ hs_bf,
              unsigned short* __restrict__ wqkv, unsigned short* __restrict__ wo_bf)
{
    const int i = (blockIdx.x * 256 + threadIdx.x) * 4;
    const float* s; unsigned short* d;
    if (i < 8388608)       { s = hs + i;             d = hs_bf + i; }
    else if (i < 8650752)  { s = wq + (i - 8388608); d = wqkv + (i - 8388608); }
    else if (i < 8912896)  { s = wk + (i - 8650752); d = wqkv + 262144 + (i - 8650752); }
    else if (i < 9961472)  { s = wv + (i - 8912896); d = wqkv + 524288 + (i - 8912896); }
    else if (i < 11010048) { s = wo + (i - 9961472); d = wo_bf + (i - 9961472); }
    else return;
    float4 v = *(const float4*)s;
    ushort4 o; o.x = f2b(v.x); o.y = f2b(v.y); o.z = f2b(v.z); o.w = f2b(v.w);
    *(ushort4*)d = o;
}

// ---------------------------------------------------------------------------
// bf16 MFMA GEMM: C[M,N] = A[M,K] @ Bw[N,K]^T (fp32 acc), strided.
// 128x128 tile, BK=32, 256 threads, m97 recipe (global_load_lds width-16).
// ---------------------------------------------------------------------------
template <typename OutT>
__global__ __launch_bounds__(256)
void gemm_bf16(const unsigned short* __restrict__ A, const unsigned short* __restrict__ Bw,
               OutT* __restrict__ C, int M, int N, int K, int lda, int ldb, int ldc)
{
    __shared__ unsigned short As[128 * 32];
    __shared__ unsigned short Bs[128 * 32];
    const int tid  = threadIdx.x;
    const int wave = tid >> 6, lane = tid & 63;
    const int m0 = blockIdx.y * 128, n0 = blockIdx.x * 128;
    const int wm = (wave >> 1) * 64, wn = (wave & 1) * 64;
    const int srow = tid >> 2;
    const int skc  = tid & 3;
    const int ml = lane & 15, qq = lane >> 4;

    f32x4_t acc[4][4];
#pragma unroll
    for (int i = 0; i < 4; ++i)
#pragma unroll
        for (int j = 0; j < 4; ++j) acc[i][j] = (f32x4_t){0.f, 0.f, 0.f, 0.f};

    for (int k0 = 0; k0 < K; k0 += 32) {
#pragma unroll
        for (int p = 0; p < 2; ++p) {
            const int row = p * 64 + srow;
            const unsigned short* ga = A  + (size_t)(m0 + row) * lda + k0 + skc * 8;
            const unsigned short* gb = Bw + (size_t)(n0 + row) * ldb + k0 + skc * 8;
            unsigned short* la = As + (size_t)(p * 64 + wave * 16) * 32;
            unsigned short* lb = Bs + (size_t)(p * 64 + wave * 16) * 32;
            __builtin_amdgcn_global_load_lds((const __attribute__((address_space(1))) void*)ga,
                                             (__attribute__((address_space(3))) void*)la, 16, 0, 0);
            __builtin_amdgcn_global_load_lds((const __attribute__((address_space(1))) void*)gb,
                                             (__attribute__((address_space(3))) void*)lb, 16, 0, 0);
        }
        __syncthreads();
        bf16x8_t af[4], bfr[4];
#pragma unroll
        for (int i = 0; i < 4; ++i) {
            af[i]  = *(const bf16x8_t*)(As + (wm + i * 16 + ml) * 32 + qq * 8);
            bfr[i] = *(const bf16x8_t*)(Bs + (wn + i * 16 + ml) * 32 + qq * 8);
        }
#pragma unroll
        for (int i = 0; i < 4; ++i)
#pragma unroll
            for (int j = 0; j < 4; ++j)
                acc[i][j] = __builtin_amdgcn_mfma_f32_16x16x32_bf16(af[i], bfr[j], acc[i][j], 0, 0, 0);
        __syncthreads();
    }
#pragma unroll
    for (int i = 0; i < 4; ++i) {
        const int rbase = m0 + wm + i * 16 + qq * 4;
#pragma unroll
        for (int j = 0; j < 4; ++j) {
            const int col = n0 + wn + j * 16 + ml;
#pragma unroll
            for (int r = 0; r < 4; ++r) {
                const float v = acc[i][j][r];
                if constexpr (sizeof(OutT) == 2) {
                    ((unsigned short*)C)[(size_t)(rbase + r) * ldc + col] = f2b(v);
                } else {
                    ((float*)C)[(size_t)(rbase + r) * ldc + col] = v;
                }
            }
        }
    }
}

// ---------------------------------------------------------------------------
// state_kernel: per (bh,c) computes S_c = Kf^T @ V_ext (MFMA), stored in the
// TILED layout: slab[dtile 0..17][e 0..79][dlocal 0..15], d = dtile*16+dlocal.
// Feature order d: [1][q/2 x16][0 x7][qxq/(4sqrt2) x256][0 x8]; e=64 -> z.
// ---------------------------------------------------------------------------
__global__ __launch_bounds__(256)
void state_kernel(const unsigned short* __restrict__ qkv, unsigned short* __restrict__ STg)
{
    __shared__ unsigned short KT[16 * 136];   // K transposed [f][j], padded
    __shared__ unsigned short VT[80 * 136];   // V_ext transposed [e][j], padded

    const int x = blockIdx.x;
    const int c = x & 15, bh = x >> 4;
    const int b = bh >> 4, h = bh & 15;
    const int tid = threadIdx.x;
    const int wave = tid >> 6, lane = tid & 63;
    const int ml = lane & 15, kg8 = (lane >> 4) * 8;
    const size_t rowbase = (size_t)(b * LL + c * CHUNK);
    const size_t Sbase = (size_t)x * SROW;

    {
        const int row = tid >> 1, half = tid & 1;
        uint4 kv = *(const uint4*)(qkv + (rowbase + row) * QKVLD + 256 + h * 16 + half * 8);
        const unsigned short* kp = (const unsigned short*)&kv;
#pragma unroll
        for (int i = 0; i < 8; ++i) KT[(half * 8 + i) * 136 + row] = kp[i];
#pragma unroll
        for (int cc = 0; cc < 4; ++cc) {
            uint4 vv = *(const uint4*)(qkv + (rowbase + row) * QKVLD + 512 + h * 64 + half * 32 + cc * 8);
            const unsigned short* vp = (const unsigned short*)&vv;
#pragma unroll
            for (int i = 0; i < 8; ++i) VT[(half * 32 + cc * 8 + i) * 136 + row] = vp[i];
        }
        if (half == 0) {
            VT[64 * 136 + row] = 0x3F80;   // ones column
        } else {
#pragma unroll
            for (int e = 65; e < 80; ++e) VT[e * 136 + row] = 0;
        }
    }
    __syncthreads();

    bf16x8_t bfr[5][4];
#pragma unroll
    for (int nt = 0; nt < 5; ++nt)
#pragma unroll
        for (int ks = 0; ks < 4; ++ks)
            bfr[nt][ks] = *(const bf16x8_t*)&VT[(nt * 16 + ml) * 136 + ks * 32 + kg8];

    for (int mt = wave; mt < 18; mt += 4) {
        const int d = mt * 16 + ml;
        bf16x8_t af[4];
#pragma unroll
        for (int ks = 0; ks < 4; ++ks) {
            const int jb = ks * 32 + kg8;
            unsigned short o[8];
            if (d >= 24 && d < 280) {
                const int e = d - 24, a = e >> 4, bq = e & 15;
                bf16x8_t ka = *(const bf16x8_t*)&KT[a  * 136 + jb];
                bf16x8_t kb = *(const bf16x8_t*)&KT[bq * 136 + jb];
#pragma unroll
                for (int j = 0; j < 8; ++j)
                    o[j] = f2b(b2f((unsigned short)ka[j]) * b2f((unsigned short)kb[j]) * INV_R2RD);
            } else if (d == 0) {
#pragma unroll
                for (int j = 0; j < 8; ++j) o[j] = 0x3F80;
            } else if (d <= 16) {
                bf16x8_t kx = *(const bf16x8_t*)&KT[(d - 1) * 136 + jb];
#pragma unroll
                for (int j = 0; j < 8; ++j) o[j] = f2b(b2f((unsigned short)kx[j]) * 0.5f);
            } else {
#pragma unroll
                for (int j = 0; j < 8; ++j) o[j] = 0;
            }
            af[ks] = *(const bf16x8_t*)o;
        }
        f32x4_t acc[5];
#pragma unroll
        for (int nt = 0; nt < 5; ++nt) acc[nt] = (f32x4_t){0.f, 0.f, 0.f, 0.f};
#pragma unroll
        for (int nt = 0; nt < 5; ++nt)
#pragma unroll
            for (int ks = 0; ks < 4; ++ks)
                acc[nt] = __builtin_amdgcn_mfma_f32_16x16x32_bf16(af[ks], bfr[nt][ks], acc[nt], 0, 0, 0);
        // tiled store: slab[mt][e = nt*16+ml][dlocal = quad*4 + r]
#pragma unroll
        for (int nt = 0; nt < 5; ++nt) {
            ushort4 pk;
            pk.x = f2b(acc[nt][0]); pk.y = f2b(acc[nt][1]);
            pk.z = f2b(acc[nt][2]); pk.w = f2b(acc[nt][3]);
            *(ushort4*)(STg + Sbase + (size_t)mt * 1280 + (nt * 16 + ml) * 16 + (lane >> 4) * 4) = pk;
        }
    }
}

// ---------------------------------------------------------------------------
// scan: exclusive prefix over the 16 chunks, elementwise, uint4 per thread.
// ---------------------------------------------------------------------------
__global__ __launch_bounds__(256)
void scan_S(unsigned short* __restrict__ STg) {
    const int bh  = blockIdx.y;
    const int idx = blockIdx.x * 256 + threadIdx.x;   // uint4 index, 0..2879
    if (idx >= SROW / 8) return;
    const size_t base = (size_t)bh * NCHUNK * SROW + (size_t)idx * 8;
    float acc[8] = {};
    for (int c = 0; c < NCHUNK; ++c) {
        unsigned short* p = STg + base + (size_t)c * SROW;
        uint4 v = *(const uint4*)p;
        const unsigned short* vp = (const unsigned short*)&v;
        uint4 o;
        unsigned short* op = (unsigned short*)&o;
#pragma unroll
        for (int i = 0; i < 8; ++i) { op[i] = f2b(acc[i]); acc[i] += b2f(vp[i]); }
        *(uint4*)p = o;
    }
}

// ---------------------------------------------------------------------------
// out_kernel: per (bh,c), 256 threads / 4 waves.
// Phase 1: A = poly(Q K^T / 4) masked (MFMA), A staged bf16 in LDS.
// Phase 2a: Y += A @ V_ext (MFMA, VT in LDS).
// Phase 2b: Y += Qf @ S_ext — BARRIER-FREE: B-fragments loaded directly
//   global->VGPR from the tiled ST slab, double-buffered (prefetch kq+1
//   during MFMA of kq; slice 0 issued at kernel top).
// LDS (ushort units): Qpad[128*40]@0 + Kpad[128*40]@5120 (VT[80*136]@0
// overlays both after phase 1) | A[128*136]@10880 | Qs[128*16]@28288.
// ---------------------------------------------------------------------------
#define OFF_VT 0
#define OFF_QP 0
#define OFF_KP 5120
#define OFF_A  10880
#define OFF_QS 28288

__global__ __launch_bounds__(256)
void out_kernel(const unsigned short* __restrict__ qkv_ro, const unsigned short* __restrict__ STg,
                unsigned short* __restrict__ qkv_w)
{
    __shared__ unsigned short smem[30336];   // 60672 B

    const int x = blockIdx.x;
    const int c = x & 15, bh = x >> 4;
    const int b = bh >> 4, h = bh & 15;
    const int tid = threadIdx.x;
    const int w = tid >> 6, lane = tid & 63;
    const int ml = lane & 15, quad = lane >> 4, kg8 = quad * 8;
    const size_t rowbase = (size_t)(b * LL + c * CHUNK);
    const size_t Sbase = (size_t)x * SROW;

    // ---- early prefetch of ST slice kq=0 (in flight through phase 1) ----
    const unsigned short* stp = STg + Sbase + (size_t)(quad >> 1) * 1280 + (quad & 1) * 8;
    bf16x8_t stf[2][5];
#pragma unroll
    for (int nt = 0; nt < 5; ++nt)
        stf[0][nt] = *(const bf16x8_t*)(stp + (nt * 16 + ml) * 16);

    // ---- load Q (padded + small) and K (padded) ----
    {
        const int row = tid >> 1, half = tid & 1;
        uint4 qv = *(const uint4*)(qkv_ro + (rowbase + row) * QKVLD + h * 16 + half * 8);
        *(uint4*)&smem[OFF_QP + row * 40 + half * 8] = qv;
        *(uint4*)&smem[OFF_QP + row * 40 + 16 + half * 8] = (uint4){0, 0, 0, 0};
        *(uint4*)&smem[OFF_QS + row * 16 + half * 8] = qv;
        uint4 kv = *(const uint4*)(qkv_ro + (rowbase + row) * QKVLD + 256 + h * 16 + half * 8);
        *(uint4*)&smem[OFF_KP + row * 40 + half * 8] = kv;
        *(uint4*)&smem[OFF_KP + row * 40 + 16 + half * 8] = (uint4){0, 0, 0, 0};
    }
    __syncthreads();

    // ---- phase 1: scores ----
    {
        bf16x8_t q0 = *(const bf16x8_t*)&smem[OFF_QP + (w * 32 + ml) * 40 + kg8];
        bf16x8_t q1 = *(const bf16x8_t*)&smem[OFF_QP + (w * 32 + 16 + ml) * 40 + kg8];
#pragma unroll
        for (int nt = 0; nt < 8; ++nt) {
            bf16x8_t kf = *(const bf16x8_t*)&smem[OFF_KP + (nt * 16 + ml) * 40 + kg8];
            f32x4_t a0 = __builtin_amdgcn_mfma_f32_16x16x32_bf16(q0, kf, (f32x4_t){0,0,0,0}, 0, 0, 0);
            f32x4_t a1 = __builtin_amdgcn_mfma_f32_16x16x32_bf16(q1, kf, (f32x4_t){0,0,0,0}, 0, 0, 0);
            const int j = nt * 16 + ml;
#pragma unroll
            for (int r = 0; r < 4; ++r) {
                int i0 = w * 32 + quad * 4 + r;
                float s0 = a0[r] * 0.25f;
                float v0 = (j <= i0) ? (1.f + s0 + 0.5f * s0 * s0) : 0.f;
                smem[OFF_A + i0 * 136 + j] = f2b(v0);
                int i1 = i0 + 16;
                float s1 = a1[r] * 0.25f;
                float v1 = (j <= i1) ? (1.f + s1 + 0.5f * s1 * s1) : 0.f;
                smem[OFF_A + i1 * 136 + j] = f2b(v1);
            }
        }
    }
    // q f32 registers for Qf build
    const int r0 = w * 32 + ml, r1 = r0 + 16;
    float qA[16], qB[16];
    {
        bf16x8_t t0 = *(const bf16x8_t*)&smem[OFF_QS + r0 * 16];
        bf16x8_t t1 = *(const bf16x8_t*)&smem[OFF_QS + r0 * 16 + 8];
        bf16x8_t t2 = *(const bf16x8_t*)&smem[OFF_QS + r1 * 16];
        bf16x8_t t3 = *(const bf16x8_t*)&smem[OFF_QS + r1 * 16 + 8];
#pragma unroll
        for (int i = 0; i < 8; ++i) {
            qA[i] = b2f((unsigned short)t0[i]); qA[8 + i] = b2f((unsigned short)t1[i]);
            qB[i] = b2f((unsigned short)t2[i]); qB[8 + i] = b2f((unsigned short)t3[i]);
        }
    }
    __syncthreads();   // A-writes + Qpad/Kpad reads done before VT overlay

    // ---- load VT (overlays Qpad/Kpad) ----
    {
        const int row = tid >> 1, half = tid & 1;
#pragma unroll
        for (int cc = 0; cc < 4; ++cc) {
            uint4 vv = *(const uint4*)(qkv_ro + (rowbase + row) * QKVLD + 512 + h * 64 + half * 32 + cc * 8);
            const unsigned short* vp = (const unsigned short*)&vv;
#pragma unroll
            for (int i = 0; i < 8; ++i) smem[OFF_VT + (half * 32 + cc * 8 + i) * 136 + row] = vp[i];
        }
        if (half == 0) {
            smem[OFF_VT + 64 * 136 + row] = 0x3F80;
        } else {
#pragma unroll
            for (int e = 65; e < 80; ++e) smem[OFF_VT + e * 136 + row] = 0;
        }
    }
    __syncthreads();

    f32x4_t acc[2][5];
#pragma unroll
    for (int mt = 0; mt < 2; ++mt)
#pragma unroll
        for (int nt = 0; nt < 5; ++nt) acc[mt][nt] = (f32x4_t){0.f, 0.f, 0.f, 0.f};

    // ---- phase 2a: A @ V_ext ----
#pragma unroll
    for (int ks = 0; ks < 4; ++ks) {
        bf16x8_t af0 = *(const bf16x8_t*)&smem[OFF_A + (w * 32 + ml) * 136 + ks * 32 + kg8];
        bf16x8_t af1 = *(const bf16x8_t*)&smem[OFF_A + (w * 32 + 16 + ml) * 136 + ks * 32 + kg8];
#pragma unroll
        for (int nt = 0; nt < 5; ++nt) {
            bf16x8_t bv = *(const bf16x8_t*)&smem[OFF_VT + (nt * 16 + ml) * 136 + ks * 32 + kg8];
            acc[0][nt] = __builtin_amdgcn_mfma_f32_16x16x32_bf16(af0, bv, acc[0][nt], 0, 0, 0);
            acc[1][nt] = __builtin_amdgcn_mfma_f32_16x16x32_bf16(af1, bv, acc[1][nt], 0, 0, 0);
        }
    }

    // ---- phase 2b: Qf @ S_ext, barrier-free, double-buffered global reads ----
#pragma unroll
    for (int kq = 0; kq < 9; ++kq) {
        if (kq < 8) {
#pragma unroll
            for (int nt = 0; nt < 5; ++nt)
                stf[(kq + 1) & 1][nt] =
                    *(const bf16x8_t*)(stp + (size_t)(kq + 1) * 2560 + (nt * 16 + ml) * 16);
        }
        bf16x8_t qf[2];
#pragma unroll
        for (int mt = 0; mt < 2; ++mt) {
            const float* q = (mt == 0) ? qA : qB;
            const int qsrow = (mt == 0) ? r0 : r1;
            const int d0 = kq * 32 + kg8;
            unsigned short o[8];
            if (d0 >= 24 && d0 < 280) {
                const int e0 = d0 - 24;
                const float qa = b2f(smem[OFF_QS + qsrow * 16 + (e0 >> 4)]) * INV_R2RD;
                if ((e0 & 15) == 0) {
#pragma unroll
                    for (int j = 0; j < 8; ++j) o[j] = f2b(qa * q[j]);
                } else {
#pragma unroll
                    for (int j = 0; j < 8; ++j) o[j] = f2b(qa * q[8 + j]);
                }
            } else if (d0 == 0) {
                o[0] = 0x3F80;
#pragma unroll
                for (int j = 1; j < 8; ++j) o[j] = f2b(q[j - 1] * 0.5f);
            } else if (d0 == 8) {
#pragma unroll
                for (int j = 0; j < 8; ++j) o[j] = f2b(q[7 + j] * 0.5f);
            } else if (d0 == 16) {
                o[0] = f2b(q[15] * 0.5f);
#pragma unroll
                for (int j = 1; j < 8; ++j) o[j] = 0;
            } else {
#pragma unroll
                for (int j = 0; j < 8; ++j) o[j] = 0;
            }
            qf[mt] = *(const bf16x8_t*)o;
        }
#pragma unroll
        for (int nt = 0; nt < 5; ++nt) {
            acc[0][nt] = __builtin_amdgcn_mfma_f32_16x16x32_bf16(qf[0], stf[kq & 1][nt], acc[0][nt], 0, 0, 0);
            acc[1][nt] = __builtin_amdgcn_mfma_f32_16x16x32_bf16(qf[1], stf[kq & 1][nt], acc[1][nt], 0, 0, 0);
        }
    }

    // ---- epilogue: y = num / (den + eps), den = col 64 (nt=4, ml==0 lanes) ----
#pragma unroll
    for (int mt = 0; mt < 2; ++mt) {
        float den[4];
#pragma unroll
        for (int r = 0; r < 4; ++r) den[r] = __shfl(acc[mt][4][r], lane & 48);
#pragma unroll
        for (int r = 0; r < 4; ++r) {
            const size_t grow = rowbase + w * 32 + mt * 16 + quad * 4 + r;
            const float rc = 1.f / (den[r] + EPS);
#pragma unroll
            for (int nt = 0; nt < 4; ++nt)
                qkv_w[grow * QKVLD + 512 + h * 64 + nt * 16 + ml] = f2b(acc[mt][nt][r] * rc);
        }
    }
}

// ---------------------------------------------------------------------------
extern "C" void kernel_launch(void* const* d_in, const int* in_sizes, int n_in,
                              void* d_out, int out_size, void* d_ws, size_t ws_size,
                              hipStream_t stream)
{
    (void)in_sizes; (void)n_in; (void)out_size; (void)ws_size;
    const float* hs = (const float*)d_in[0];
    const float* Wq = (const float*)d_in[1];
    const float* Wk = (const float*)d_in[2];
    const float* Wv = (const float*)d_in[3];
    const float* Wo = (const float*)d_in[4];
    float* out = (float*)d_out;

    const int M = BB * LL;  // 8192
    char* ws = (char*)d_ws;
    // S region (47,185,920 B) at 0; hs_bf (16 MB) aliases its start (dead
    // before state_kernel writes S).
    unsigned short* STg   = (unsigned short*)ws;
    unsigned short* hs_bf = (unsigned short*)ws;
    size_t off = 47185920;
    unsigned short* qkv   = (unsigned short*)(ws + off); off += 25165824;  // 8192x1536
    unsigned short* Wqkv  = (unsigned short*)(ws + off); off += 3145728;   // 1536x1024
    unsigned short* Wo_bf = (unsigned short*)(ws + off); off += 2097152;   // total 77.6 MB

    cast_all<<<10752, 256, 0, stream>>>(hs, Wq, Wk, Wv, Wo, hs_bf, Wqkv, Wo_bf);
    gemm_bf16<unsigned short><<<dim3(12, 64), 256, 0, stream>>>(hs_bf, Wqkv, qkv,
                                                                M, 1536, DM, DM, DM, QKVLD);
    state_kernel<<<1024, 256, 0, stream>>>(qkv, STg);
    scan_S<<<dim3(12, 64), 256, 0, stream>>>(STg);
    out_kernel<<<1024, 256, 0, stream>>>(qkv, STg, qkv);   // y in-place over v cols
    gemm_bf16<float><<<dim3(8, 64), 256, 0, stream>>>(qkv + 512, Wo_bf, out,
                                                      M, DM, DM, QKVLD, DM, DM);
}